// Round 1
// baseline (611.066 us; speedup 1.0000x reference)
//
#include <hip/hip_runtime.h>
#include <stdint.h>

#define H_   16
#define NS_  2048
#define B_   4
#define DM_  1024
#define HD_  64
#define MTOT (B_*NS_)   // 8192 tokens

typedef __attribute__((ext_vector_type(8))) short bf16x8;
typedef __attribute__((ext_vector_type(4))) float f32x4;

__device__ __forceinline__ unsigned short f2bf(float f){
  union { float f; unsigned u; } v; v.f = f;
  unsigned r = v.u + 0x7FFFu + ((v.u >> 16) & 1u);
  return (unsigned short)(r >> 16);
}
__device__ __forceinline__ float bf2f(unsigned short u){
  union { unsigned u; float f; } v; v.u = ((unsigned)u) << 16;
  return v.f;
}

__device__ __forceinline__ void gll16(const void* g, void* l){
  __builtin_amdgcn_global_load_lds(
      (const __attribute__((address_space(1))) unsigned int*)g,
      (__attribute__((address_space(3))) unsigned int*)l,
      16, 0, 0);
}

// ---------------- cast hidden_states fp32 -> bf16 ----------------
__global__ void k_cast_x(const float* __restrict__ x, unsigned short* __restrict__ xb){
  long i = ((long)blockIdx.x*256 + threadIdx.x)*4;
  float4 v = *(const float4*)(x + i);
  ushort4 o; o.x=f2bf(v.x); o.y=f2bf(v.y); o.z=f2bf(v.z); o.w=f2bf(v.w);
  *(ushort4*)(xb + i) = o;
}

// ---------------- transpose-cast weight: W[k][n] fp32 -> Wt[n][k] bf16 ----------------
__global__ void k_wt(const float* __restrict__ W, unsigned short* __restrict__ Wt){
  __shared__ float tile[64][65];
  int kt = blockIdx.y*64, nt = blockIdx.x*64;
  int t = threadIdx.x;
  int r = t >> 4, c4 = (t & 15)*4;
#pragma unroll
  for (int i=0;i<4;i++){
    int k = r + i*16;
    float4 v = *(const float4*)(W + (size_t)(kt + k)*DM_ + nt + c4);
    tile[k][c4] = v.x; tile[k][c4+1]=v.y; tile[k][c4+2]=v.z; tile[k][c4+3]=v.w;
  }
  __syncthreads();
#pragma unroll
  for (int i=0;i<4;i++){
    int n = r + i*16;
    ushort4 o;
    o.x = f2bf(tile[c4+0][n]); o.y = f2bf(tile[c4+1][n]);
    o.z = f2bf(tile[c4+2][n]); o.w = f2bf(tile[c4+3][n]);
    *(ushort4*)(Wt + (size_t)(nt + n)*DM_ + kt + c4) = o;
  }
}

// ---------------- RoPE sin/cos table: tab[n][c*10+i] = (cos,sin) ----------------
__global__ void k_tab(float2* __restrict__ tab){
  int n = blockIdx.x*64 + threadIdx.x;   // grid 32 x 64
  int f = n >> 8, rem = n & 255, hh = rem >> 4, ww = rem & 15;
  float pos[3]; pos[0]=(float)f; pos[1]=(float)hh; pos[2]=(float)ww;
#pragma unroll
  for (int c=0;c<3;c++)
#pragma unroll
    for (int i=0;i<10;i++){
      float inv = exp2f(-(float)i * 1.3287712379549449f);  // 10000^(-i/10)
      float s, co;
      sincosf(pos[c]*inv, &s, &co);
      tab[n*30 + c*10 + i] = make_float2(co, s);
    }
}

// ---------------- GEMM: A(8192x1024 bf16) @ Wt^T  (Wt is [n][k]) ----------------
// MODE 0: out bf16 in (B,H,N,64) layout, +bias
// MODE 1: out fp32 row-major (8192x1024), +bias
template<int MODE>
__global__ __launch_bounds__(256) void k_gemm(const unsigned short* __restrict__ A,
                                              const unsigned short* __restrict__ Wt,
                                              const float* __restrict__ bias,
                                              void* __restrict__ outp)
{
  __shared__ unsigned short As[128*32];
  __shared__ unsigned short Bs[128*32];
  const int tid = threadIdx.x, lane = tid & 63, w = tid >> 6;
  const int mt = blockIdx.y*128, nt = blockIdx.x*128;
  const int wm = (w >> 1)*64, wn = (w & 1)*64;
  const int qc = lane & 15, g = lane >> 4;
  f32x4 acc[4][4] = {};

  const unsigned short* gA = A  + (size_t)(mt + w*32 + (lane>>2))*DM_ + (lane&3)*8;
  const unsigned short* gB = Wt + (size_t)(nt + w*32 + (lane>>2))*DM_ + (lane&3)*8;
  unsigned short* lA = &As[(w*32)*32];
  unsigned short* lB = &Bs[(w*32)*32];

  for (int k0 = 0; k0 < DM_; k0 += 32){
    gll16(gA + k0,           lA);
    gll16(gA + k0 + 16*DM_,  lA + 16*32);
    gll16(gB + k0,           lB);
    gll16(gB + k0 + 16*DM_,  lB + 16*32);
    __syncthreads();
    bf16x8 af[4], bfr[4];
#pragma unroll
    for (int m=0;m<4;m++) af[m]  = *(const bf16x8*)&As[(wm + m*16 + qc)*32 + g*8];
#pragma unroll
    for (int n=0;n<4;n++) bfr[n] = *(const bf16x8*)&Bs[(wn + n*16 + qc)*32 + g*8];
#pragma unroll
    for (int m=0;m<4;m++)
#pragma unroll
      for (int n=0;n<4;n++)
        acc[m][n] = __builtin_amdgcn_mfma_f32_16x16x32_bf16(af[m], bfr[n], acc[m][n], 0,0,0);
    __syncthreads();
  }

  if (MODE == 0){
    unsigned short* out = (unsigned short*)outp;
#pragma unroll
    for (int n=0;n<4;n++){
      int col = nt + wn + n*16 + qc;
      float bv = bias[col];
      int h = col >> 6, d = col & 63;
#pragma unroll
      for (int m=0;m<4;m++){
#pragma unroll
        for (int r=0;r<4;r++){
          int mrow = mt + wm + m*16 + g*4 + r;
          size_t idx = (((size_t)(mrow >> 11)*H_ + h)*NS_ + (mrow & (NS_-1)))*HD_ + d;
          out[idx] = f2bf(acc[m][n][r] + bv);
        }
      }
    }
  } else {
    float* out = (float*)outp;
#pragma unroll
    for (int n=0;n<4;n++){
      int col = nt + wn + n*16 + qc;
      float bv = bias[col];
#pragma unroll
      for (int m=0;m<4;m++){
#pragma unroll
        for (int r=0;r<4;r++){
          int mrow = mt + wm + m*16 + g*4 + r;
          out[(size_t)mrow*DM_ + col] = acc[m][n][r] + bv;
        }
      }
    }
  }
}

// ---------------- in-place RoPE on Q,K in (B,H,N,64) ----------------
__global__ void k_rope(unsigned short* __restrict__ Qb, unsigned short* __restrict__ Kb,
                       const float2* __restrict__ tab)
{
  const int t = threadIdx.x;
  const int d4 = (t & 15)*4;
  if (d4 >= 60) return;                       // dims 60..63 pass through
  const long gtok = (long)blockIdx.x*16 + (t >> 4);   // bh*2048 + n
  const int n = (int)(gtok & (NS_-1));
  const int c = d4 / 20;
  const int dd = d4 - c*20;
  const float2* tb = tab + n*30 + c*10;
  float2 cs0 = tb[(dd+0) % 10];
  float2 cs1 = tb[(dd+1) % 10];
  float2 cs2 = tb[(dd+2) % 10];
  float2 cs3 = tb[(dd+3) % 10];
  size_t base = (size_t)gtok*HD_ + d4;
#pragma unroll
  for (int which = 0; which < 2; which++){
    unsigned short* P = which ? Kb : Qb;
    ushort4 v = *(ushort4*)(P + base);
    float x0=bf2f(v.x), x1=bf2f(v.y), x2=bf2f(v.z), x3=bf2f(v.w);
    ushort4 o;
    o.x = f2bf(x0*cs0.x - x1*cs0.y);
    o.y = f2bf(x1*cs1.x + x0*cs1.y);
    o.z = f2bf(x2*cs2.x - x3*cs2.y);
    o.w = f2bf(x3*cs3.x + x2*cs3.y);
    *(ushort4*)(P + base) = o;
  }
}

// ---------------- V (B,H,N,64) -> VT (B,H,64,N) via per-lane register transpose ----------------
__global__ void k_vt(const unsigned short* __restrict__ V, unsigned short* __restrict__ VT){
  const int lane = threadIdx.x & 63, w = threadIdx.x >> 6;
  const int wg = blockIdx.x*4 + w;        // 0..2047
  const int bh = wg >> 5;
  const int n0 = (wg & 31)*64;
  const unsigned short* src = V + ((size_t)bh*NS_ + n0 + lane)*HD_;
  uint4 rv[8];
#pragma unroll
  for (int i=0;i<8;i++) rv[i] = *(const uint4*)(src + i*8);
  const unsigned short* vals = (const unsigned short*)rv;
  unsigned short* dst = VT + (size_t)bh*HD_*NS_ + n0 + lane;
#pragma unroll
  for (int d=0; d<64; d++)
    dst[(size_t)d*NS_] = vals[d];
}

// ---------------- flash attention: swapped QK^T, ctx^T = V^T @ P^T ----------------
__global__ __launch_bounds__(256) void k_attn(const unsigned short* __restrict__ Q,
                                              const unsigned short* __restrict__ K,
                                              const unsigned short* __restrict__ VT,
                                              unsigned short* __restrict__ ctx)
{
  const int lane = threadIdx.x & 63, w = threadIdx.x >> 6;
  const int bh = blockIdx.y;
  const int q0 = blockIdx.x*64 + w*16;
  const int qc = lane & 15, g = lane >> 4;
  const unsigned short* Qp = Q  + ((size_t)bh*NS_ + q0)*HD_;
  const unsigned short* Kp = K  + (size_t)bh*NS_*HD_;
  const unsigned short* Vp = VT + (size_t)bh*HD_*NS_;

  bf16x8 qf0 = *(const bf16x8*)(Qp + qc*HD_ + g*8);
  bf16x8 qf1 = *(const bf16x8*)(Qp + qc*HD_ + 32 + g*8);

  f32x4 ct[4] = {};
  float mrun = -3e38f, lrun = 0.f;
  const int srcLo = qc + 32*(g & 1);
  const int srcHi = srcLo + 16;
  const bool hi_s = (g >= 2);

  for (int kb = 0; kb < NS_; kb += 32){
    const unsigned short* kr = Kp + (size_t)(kb + qc)*HD_;
    bf16x8 k0a = *(const bf16x8*)(kr + g*8);
    bf16x8 k0b = *(const bf16x8*)(kr + 32 + g*8);
    bf16x8 k1a = *(const bf16x8*)(kr + 16*HD_ + g*8);
    bf16x8 k1b = *(const bf16x8*)(kr + 16*HD_ + 32 + g*8);
    f32x4 st0 = {}, st1 = {};
    st0 = __builtin_amdgcn_mfma_f32_16x16x32_bf16(k0a, qf0, st0, 0,0,0);
    st0 = __builtin_amdgcn_mfma_f32_16x16x32_bf16(k0b, qf1, st0, 0,0,0);
    st1 = __builtin_amdgcn_mfma_f32_16x16x32_bf16(k1a, qf0, st1, 0,0,0);
    st1 = __builtin_amdgcn_mfma_f32_16x16x32_bf16(k1b, qf1, st1, 0,0,0);

    float p0[4], p1[4];
    float tmax = -3e38f;
#pragma unroll
    for (int r=0;r<4;r++){
      p0[r] = st0[r]*0.125f; p1[r] = st1[r]*0.125f;
      tmax = fmaxf(tmax, fmaxf(p0[r], p1[r]));
    }
    tmax = fmaxf(tmax, __shfl_xor(tmax, 16));
    tmax = fmaxf(tmax, __shfl_xor(tmax, 32));
    float mnew = fmaxf(mrun, tmax);
    float alpha = __expf(mrun - mnew);
    float ps = 0.f;
#pragma unroll
    for (int r=0;r<4;r++){
      p0[r] = __expf(p0[r] - mnew);
      p1[r] = __expf(p1[r] - mnew);
      ps += p0[r] + p1[r];
    }
    ps += __shfl_xor(ps, 16);
    ps += __shfl_xor(ps, 32);
    lrun = lrun*alpha + ps;
    mrun = mnew;
#pragma unroll
    for (int t=0;t<4;t++){
      ct[t][0]*=alpha; ct[t][1]*=alpha; ct[t][2]*=alpha; ct[t][3]*=alpha;
    }

    // redistribute P^T into B-operand fragment: lane needs keys kb + 8g + j
    bf16x8 pf;
#pragma unroll
    for (int r=0;r<4;r++){
      float a0 = __shfl(p0[r], srcLo), a1 = __shfl(p1[r], srcLo);
      float b0 = __shfl(p0[r], srcHi), b1 = __shfl(p1[r], srcHi);
      pf[r]   = (short)f2bf(hi_s ? a1 : a0);
      pf[4+r] = (short)f2bf(hi_s ? b1 : b0);
    }

#pragma unroll
    for (int t=0;t<4;t++){
      bf16x8 vf = *(const bf16x8*)(Vp + (size_t)(t*16 + qc)*NS_ + kb + g*8);
      ct[t] = __builtin_amdgcn_mfma_f32_16x16x32_bf16(vf, pf, ct[t], 0,0,0);
    }
  }

  float inv = 1.f / lrun;
  size_t orow = (((size_t)(bh >> 4)*NS_ + q0 + qc)*H_ + (bh & 15))*HD_;
#pragma unroll
  for (int t=0;t<4;t++){
    ushort4 o;
    o.x = f2bf(ct[t][0]*inv); o.y = f2bf(ct[t][1]*inv);
    o.z = f2bf(ct[t][2]*inv); o.w = f2bf(ct[t][3]*inv);
    *(ushort4*)(ctx + orow + t*16 + g*4) = o;
  }
}

extern "C" void kernel_launch(void* const* d_in, const int* in_sizes, int n_in,
                              void* d_out, int out_size, void* d_ws, size_t ws_size,
                              hipStream_t stream)
{
  const float* hs = (const float*)d_in[0];
  const float* Wq = (const float*)d_in[1];
  const float* bq = (const float*)d_in[2];
  const float* Wk = (const float*)d_in[3];
  const float* bk = (const float*)d_in[4];
  const float* Wv = (const float*)d_in[5];
  const float* bv = (const float*)d_in[6];
  const float* Wo = (const float*)d_in[7];
  const float* bo = (const float*)d_in[8];

  char* ws = (char*)d_ws;
  size_t off = 0;
  auto alloc = [&](size_t b){ void* p = ws + off; off += (b + 255) & ~(size_t)255; return p; };
  unsigned short* xb  = (unsigned short*)alloc((size_t)MTOT*DM_*2);
  unsigned short* wqt = (unsigned short*)alloc((size_t)DM_*DM_*2);
  unsigned short* wkt = (unsigned short*)alloc((size_t)DM_*DM_*2);
  unsigned short* wvt = (unsigned short*)alloc((size_t)DM_*DM_*2);
  unsigned short* wot = (unsigned short*)alloc((size_t)DM_*DM_*2);
  float2*         tab = (float2*)alloc((size_t)NS_*30*sizeof(float2));
  unsigned short* Qb  = (unsigned short*)alloc((size_t)MTOT*DM_*2);
  unsigned short* Kb  = (unsigned short*)alloc((size_t)MTOT*DM_*2);
  unsigned short* Vb  = (unsigned short*)alloc((size_t)MTOT*DM_*2);
  unsigned short* VTb = (unsigned short*)alloc((size_t)MTOT*DM_*2);
  unsigned short* cxb = (unsigned short*)alloc((size_t)MTOT*DM_*2);

  k_cast_x<<<dim3(MTOT*DM_/1024), dim3(256), 0, stream>>>(hs, xb);
  k_wt<<<dim3(16,16), dim3(256), 0, stream>>>(Wq, wqt);
  k_wt<<<dim3(16,16), dim3(256), 0, stream>>>(Wk, wkt);
  k_wt<<<dim3(16,16), dim3(256), 0, stream>>>(Wv, wvt);
  k_wt<<<dim3(16,16), dim3(256), 0, stream>>>(Wo, wot);
  k_tab<<<dim3(32), dim3(64), 0, stream>>>(tab);

  k_gemm<0><<<dim3(8,64), dim3(256), 0, stream>>>(xb, wqt, bq, (void*)Qb);
  k_gemm<0><<<dim3(8,64), dim3(256), 0, stream>>>(xb, wkt, bk, (void*)Kb);
  k_gemm<0><<<dim3(8,64), dim3(256), 0, stream>>>(xb, wvt, bv, (void*)Vb);

  k_rope<<<dim3(64*NS_/16), dim3(256), 0, stream>>>(Qb, Kb, tab);
  k_vt<<<dim3(512), dim3(256), 0, stream>>>(Vb, VTb);

  k_attn<<<dim3(NS_/64, 64), dim3(256), 0, stream>>>(Qb, Kb, VTb, cxb);

  k_gemm<1><<<dim3(8,64), dim3(256), 0, stream>>>(cxb, wot, bo, d_out);
}

// Round 3
// 279.402 us; speedup vs baseline: 2.1871x; 2.1871x over previous
//
#include <hip/hip_runtime.h>
#include <stdint.h>

#define H_   16
#define NS_  2048
#define B_   4
#define DM_  1024
#define HD_  64
#define MTOT (B_*NS_)   // 8192 tokens

typedef __attribute__((ext_vector_type(8)))  short bf16x8;
typedef __attribute__((ext_vector_type(4)))  short bf16x4;
typedef __attribute__((ext_vector_type(4)))  float f32x4;
typedef __attribute__((ext_vector_type(16))) float f32x16;

__device__ __forceinline__ unsigned short f2bf(float f){
  union { float f; unsigned u; } v; v.f = f;
  unsigned r = v.u + 0x7FFFu + ((v.u >> 16) & 1u);
  return (unsigned short)(r >> 16);
}
__device__ __forceinline__ float bf2f(unsigned short u){
  union { unsigned u; float f; } v; v.u = ((unsigned)u) << 16;
  return v.f;
}
__device__ __forceinline__ unsigned pk2(float a, float b){
  return (unsigned)f2bf(a) | ((unsigned)f2bf(b) << 16);
}
__device__ __forceinline__ void gll16(const void* g, void* l){
  __builtin_amdgcn_global_load_lds(
      (const __attribute__((address_space(1))) unsigned int*)g,
      (__attribute__((address_space(3))) unsigned int*)l,
      16, 0, 0);
}

// ---------------- cast hidden_states fp32 -> bf16 ----------------
__global__ void k_cast_x(const float* __restrict__ x, unsigned short* __restrict__ xb){
  long i = ((long)blockIdx.x*256 + threadIdx.x)*4;
  float4 v = *(const float4*)(x + i);
  ushort4 o; o.x=f2bf(v.x); o.y=f2bf(v.y); o.z=f2bf(v.z); o.w=f2bf(v.w);
  *(ushort4*)(xb + i) = o;
}

// ---------------- transpose-cast weight: W[k][n] fp32 -> Wt[n][k] bf16 ----------------
__global__ void k_wt(const float* __restrict__ W, unsigned short* __restrict__ Wt){
  __shared__ float tile[64][65];
  int kt = blockIdx.y*64, nt = blockIdx.x*64;
  int t = threadIdx.x;
  int r = t >> 4, c4 = (t & 15)*4;
#pragma unroll
  for (int i=0;i<4;i++){
    int k = r + i*16;
    float4 v = *(const float4*)(W + (size_t)(kt + k)*DM_ + nt + c4);
    tile[k][c4] = v.x; tile[k][c4+1]=v.y; tile[k][c4+2]=v.z; tile[k][c4+3]=v.w;
  }
  __syncthreads();
#pragma unroll
  for (int i=0;i<4;i++){
    int n = r + i*16;
    ushort4 o;
    o.x = f2bf(tile[c4+0][n]); o.y = f2bf(tile[c4+1][n]);
    o.z = f2bf(tile[c4+2][n]); o.w = f2bf(tile[c4+3][n]);
    *(ushort4*)(Wt + (size_t)(nt + n)*DM_ + kt + c4) = o;
  }
}

// ---------------- RoPE sin/cos table ----------------
__global__ void k_tab(float2* __restrict__ tab){
  int n = blockIdx.x*64 + threadIdx.x;
  int f = n >> 8, rem = n & 255, hh = rem >> 4, ww = rem & 15;
  float pos[3]; pos[0]=(float)f; pos[1]=(float)hh; pos[2]=(float)ww;
#pragma unroll
  for (int c=0;c<3;c++)
#pragma unroll
    for (int i=0;i<10;i++){
      float inv = exp2f(-(float)i * 1.3287712379549449f);  // 10000^(-i/10)
      float s, co;
      sincosf(pos[c]*inv, &s, &co);
      tab[n*30 + c*10 + i] = make_float2(co, s);
    }
}

// ---------------- GEMM (m97 structure) ----------------
template<int MODE>
__global__ __launch_bounds__(256) void k_gemm(const unsigned short* __restrict__ A,
                                              const unsigned short* __restrict__ Wt,
                                              const float* __restrict__ bias,
                                              void* __restrict__ outp)
{
  __shared__ unsigned short As[128*32];
  __shared__ unsigned short Bs[128*32];
  const int tid = threadIdx.x, lane = tid & 63, w = tid >> 6;
  const int mt = blockIdx.y*128, nt = blockIdx.x*128;
  const int wm = (w >> 1)*64, wn = (w & 1)*64;
  const int qc = lane & 15, g = lane >> 4;
  f32x4 acc[4][4] = {};

  const unsigned short* gA = A  + (size_t)(mt + w*32 + (lane>>2))*DM_ + (lane&3)*8;
  const unsigned short* gB = Wt + (size_t)(nt + w*32 + (lane>>2))*DM_ + (lane&3)*8;
  unsigned short* lA = &As[(w*32)*32];
  unsigned short* lB = &Bs[(w*32)*32];

  for (int k0 = 0; k0 < DM_; k0 += 32){
    gll16(gA + k0,           lA);
    gll16(gA + k0 + 16*DM_,  lA + 16*32);
    gll16(gB + k0,           lB);
    gll16(gB + k0 + 16*DM_,  lB + 16*32);
    __syncthreads();
    bf16x8 af[4], bfr[4];
#pragma unroll
    for (int m=0;m<4;m++) af[m]  = *(const bf16x8*)&As[(wm + m*16 + qc)*32 + g*8];
#pragma unroll
    for (int n=0;n<4;n++) bfr[n] = *(const bf16x8*)&Bs[(wn + n*16 + qc)*32 + g*8];
#pragma unroll
    for (int m=0;m<4;m++)
#pragma unroll
      for (int n=0;n<4;n++)
        acc[m][n] = __builtin_amdgcn_mfma_f32_16x16x32_bf16(af[m], bfr[n], acc[m][n], 0,0,0);
    __syncthreads();
  }

  if (MODE == 0){
    unsigned short* out = (unsigned short*)outp;
#pragma unroll
    for (int n=0;n<4;n++){
      int col = nt + wn + n*16 + qc;
      float bv = bias[col];
      int h = col >> 6, d = col & 63;
#pragma unroll
      for (int m=0;m<4;m++){
#pragma unroll
        for (int r=0;r<4;r++){
          int mrow = mt + wm + m*16 + g*4 + r;
          size_t idx = (((size_t)(mrow >> 11)*H_ + h)*NS_ + (mrow & (NS_-1)))*HD_ + d;
          out[idx] = f2bf(acc[m][n][r] + bv);
        }
      }
    }
  } else {
    float* out = (float*)outp;
#pragma unroll
    for (int n=0;n<4;n++){
      int col = nt + wn + n*16 + qc;
      float bv = bias[col];
#pragma unroll
      for (int m=0;m<4;m++){
#pragma unroll
        for (int r=0;r<4;r++){
          int mrow = mt + wm + m*16 + g*4 + r;
          out[(size_t)mrow*DM_ + col] = acc[m][n][r] + bv;
        }
      }
    }
  }
}

// ---------------- in-place RoPE on Q,K; Q additionally scaled by 1/8 ----------------
__global__ void k_rope(unsigned short* __restrict__ Qb, unsigned short* __restrict__ Kb,
                       const float2* __restrict__ tab)
{
  const int t = threadIdx.x;
  const int d4 = (t & 15)*4;
  const long gtok = (long)blockIdx.x*16 + (t >> 4);
  size_t base = (size_t)gtok*HD_ + d4;
  if (d4 >= 60){
    ushort4 v = *(ushort4*)(Qb + base);
    ushort4 o;
    o.x = f2bf(bf2f(v.x)*0.125f); o.y = f2bf(bf2f(v.y)*0.125f);
    o.z = f2bf(bf2f(v.z)*0.125f); o.w = f2bf(bf2f(v.w)*0.125f);
    *(ushort4*)(Qb + base) = o;
    return;
  }
  const int n = (int)(gtok & (NS_-1));
  const int c = d4 / 20;
  const int dd = d4 - c*20;
  const float2* tb = tab + n*30 + c*10;
  float2 cs0 = tb[(dd+0) % 10];
  float2 cs1 = tb[(dd+1) % 10];
  float2 cs2 = tb[(dd+2) % 10];
  float2 cs3 = tb[(dd+3) % 10];
#pragma unroll
  for (int which = 0; which < 2; which++){
    unsigned short* P = which ? Kb : Qb;
    float sc = which ? 1.f : 0.125f;
    ushort4 v = *(ushort4*)(P + base);
    float x0=bf2f(v.x), x1=bf2f(v.y), x2=bf2f(v.z), x3=bf2f(v.w);
    ushort4 o;
    o.x = f2bf((x0*cs0.x - x1*cs0.y)*sc);
    o.y = f2bf((x1*cs1.x + x0*cs1.y)*sc);
    o.z = f2bf((x2*cs2.x - x3*cs2.y)*sc);
    o.w = f2bf((x3*cs3.x + x2*cs3.y)*sc);
    *(ushort4*)(P + base) = o;
  }
}

// ---------------- V (B,H,N,64) -> VT (B,H,64,N) ----------------
__global__ void k_vt(const unsigned short* __restrict__ V, unsigned short* __restrict__ VT){
  const int lane = threadIdx.x & 63, w = threadIdx.x >> 6;
  const int wg = blockIdx.x*4 + w;
  const int bh = wg >> 5;
  const int n0 = (wg & 31)*64;
  const unsigned short* src = V + ((size_t)bh*NS_ + n0 + lane)*HD_;
  uint4 rv[8];
#pragma unroll
  for (int i=0;i<8;i++) rv[i] = *(const uint4*)(src + i*8);
  const unsigned short* vals = (const unsigned short*)rv;
  unsigned short* dst = VT + (size_t)bh*HD_*NS_ + n0 + lane;
#pragma unroll
  for (int d=0; d<64; d++)
    dst[(size_t)d*NS_] = vals[d];
}

// ---------------- 8-warp flash attention, 32x32 MFMA, swapped QK^T ----------------
// Per warp: 32 queries (query = lane&31, lane-local softmax). KVBLK=64.
// K & VT tiles double-buffered in LDS, XOR-swizzled (chunk ^= row&7) via
// pre-swizzled global_load_lds source. PV uses the C/D layout's natural
// key-permutation: P fragment is lane-local (pf[e] = bf16(st[e])); the
// matching V fragment is two ds_read_b64 at byte offs 64s+32kc+8h and +16.
__global__ __launch_bounds__(512, 4) void k_attn(const unsigned short* __restrict__ Q,
                                                 const unsigned short* __restrict__ K,
                                                 const unsigned short* __restrict__ VT,
                                                 unsigned short* __restrict__ ctxout)
{
  __shared__ __attribute__((aligned(16))) char smem[32768]; // 2 bufs x (8KB K + 8KB VT)
  const int tid  = threadIdx.x;
  const int lane = tid & 63, w = tid >> 6;
  const int qcol = lane & 31, h = lane >> 5;
  const int sw   = (lane & 7) << 4;
  const int bh   = blockIdx.y;
  const int q0   = blockIdx.x*256 + w*32;

  const unsigned short* Qp = Q  + ((size_t)bh*NS_ + q0)*HD_;
  const unsigned short* Kp = K  + (size_t)bh*NS_*HD_;
  const unsigned short* Vp = VT + (size_t)bh*HD_*NS_;

  // staging map: thread t covers LDS chunk (row=t>>3, c=t&7); global chunk = c ^ (row&7)
  const int trow = tid >> 3;
  const int tc   = (tid & 7) ^ (trow & 7);

  // Q fragments (B operand): col = qcol, dim = 16*i + 8*h + e
  bf16x8 qf[4];
#pragma unroll
  for (int i=0;i<4;i++)
    qf[i] = *(const bf16x8*)(Qp + (size_t)qcol*HD_ + 16*i + 8*h);

  // stage tile 0 into buffer 0
  {
    const unsigned short* gk = Kp + (size_t)trow*HD_ + tc*8;
    const unsigned short* gv = Vp + (size_t)trow*NS_ + tc*8;
    gll16(gk, smem + w*1024);
    gll16(gv, smem + 8192 + w*1024);
  }

  f32x16 ctx0 = {}, ctx1 = {};           // ctx^T: col = own query; rows = dims 0..31 / 32..63
  float mrun = -1e30f, lrun = 0.f;

  for (int t = 0; t < NS_/64; ++t){
    const int curo = (t & 1) * 16384;
    __syncthreads();                      // barrier drains vmcnt: stage(cur) complete
    if (t + 1 < NS_/64){
      const int kb = (t+1)*64;
      const int nxt = ((t+1) & 1) * 16384;
      const unsigned short* gk = Kp + (size_t)(kb + trow)*HD_ + tc*8;
      const unsigned short* gv = Vp + (size_t)trow*NS_ + kb + tc*8;
      gll16(gk, smem + nxt + w*1024);
      gll16(gv, smem + nxt + 8192 + w*1024);
    }
    const char* kls = smem + curo;
    const char* vls = smem + curo + 8192;

#pragma unroll
    for (int s = 0; s < 2; ++s){          // two 32-key subtiles
      f32x16 st = {};
#pragma unroll
      for (int i=0;i<4;i++){
        bf16x8 kf = *(const bf16x8*)(kls + ((((32*s + qcol)*128) + 32*i + 16*h) ^ sw));
        st = __builtin_amdgcn_mfma_f32_32x32x16_bf16(kf, qf[i], st, 0,0,0);
      }
      // ---- online softmax (lane-local query), defer-max THR=8 ----
      float tmax = st[0];
#pragma unroll
      for (int r=1;r<16;r++) tmax = fmaxf(tmax, st[r]);
      tmax = fmaxf(tmax, __shfl_xor(tmax, 32));
      if (!__all(tmax - mrun <= 8.f)){
        float mnew = fmaxf(mrun, tmax);
        float alpha = __expf(mrun - mnew);
        lrun *= alpha;
#pragma unroll
        for (int r=0;r<16;r++){ ctx0[r]*=alpha; ctx1[r]*=alpha; }
        mrun = mnew;
      }
      float ps = 0.f;
#pragma unroll
      for (int r=0;r<16;r++){ st[r] = __expf(st[r]-mrun); ps += st[r]; }
      ps += __shfl_xor(ps, 32);
      lrun += ps;

      // ---- P fragments: lane-local, element e = st[e] (key crow(e,h)) ----
      bf16x8 pf0, pf1;
#pragma unroll
      for (int e=0;e<8;e++){
        pf0[e] = (short)f2bf(st[e]);
        pf1[e] = (short)f2bf(st[8+e]);
      }

      // ---- PV: ctx^T += VT(dims x keys, crow-permuted) * P^T ----
#pragma unroll
      for (int half=0; half<2; ++half){
#pragma unroll
        for (int kc=0; kc<2; ++kc){
          const char* vrow = vls + (32*half + qcol)*128;
          int off = 64*s + 32*kc + 8*h;
          bf16x4 lo = *(const bf16x4*)(vrow + (off ^ sw));
          bf16x4 hi = *(const bf16x4*)(vrow + ((off + 16) ^ sw));
          bf16x8 vf;
          vf[0]=lo[0]; vf[1]=lo[1]; vf[2]=lo[2]; vf[3]=lo[3];
          vf[4]=hi[0]; vf[5]=hi[1]; vf[6]=hi[2]; vf[7]=hi[3];
          const bf16x8 pf = kc ? pf1 : pf0;
          if (half == 0) ctx0 = __builtin_amdgcn_mfma_f32_32x32x16_bf16(vf, pf, ctx0, 0,0,0);
          else           ctx1 = __builtin_amdgcn_mfma_f32_32x32x16_bf16(vf, pf, ctx1, 0,0,0);
        }
      }
    }
  }

  // ---- epilogue: per-warp LDS transpose -> coalesced stores ----
  float linv = 1.f / lrun;
  __syncthreads();                         // all warps done reading K/V LDS
  char* reg = smem + w*4096;               // 4KB per warp: [32 q][64 d] bf16
#pragma unroll
  for (int rq=0; rq<4; ++rq){
    int db0 = 8*rq + 4*h;
    uint2 v0, v1;
    v0.x = pk2(ctx0[4*rq+0]*linv, ctx0[4*rq+1]*linv);
    v0.y = pk2(ctx0[4*rq+2]*linv, ctx0[4*rq+3]*linv);
    v1.x = pk2(ctx1[4*rq+0]*linv, ctx1[4*rq+1]*linv);
    v1.y = pk2(ctx1[4*rq+2]*linv, ctx1[4*rq+3]*linv);
    *(uint2*)(reg + qcol*128 + db0*2)      = v0;
    *(uint2*)(reg + qcol*128 + (32+db0)*2) = v1;
  }
  __syncthreads();
  const int b = bh >> 4, head = bh & 15;
  unsigned short* outp = ctxout + ((size_t)b*NS_ + q0)*DM_ + head*HD_;
#pragma unroll
  for (int p=0;p<4;p++){
    int row = p*8 + (lane>>3);
    uint4 v = *(const uint4*)(reg + row*128 + (lane&7)*16);
    *(uint4*)(outp + (size_t)row*DM_ + (lane&7)*8) = v;
  }
}

extern "C" void kernel_launch(void* const* d_in, const int* in_sizes, int n_in,
                              void* d_out, int out_size, void* d_ws, size_t ws_size,
                              hipStream_t stream)
{
  const float* hs = (const float*)d_in[0];
  const float* Wq = (const float*)d_in[1];
  const float* bq = (const float*)d_in[2];
  const float* Wk = (const float*)d_in[3];
  const float* bk = (const float*)d_in[4];
  const float* Wv = (const float*)d_in[5];
  const float* bv = (const float*)d_in[6];
  const float* Wo = (const float*)d_in[7];
  const float* bo = (const float*)d_in[8];

  char* ws = (char*)d_ws;
  size_t off = 0;
  auto alloc = [&](size_t b){ void* p = ws + off; off += (b + 255) & ~(size_t)255; return p; };
  unsigned short* xb  = (unsigned short*)alloc((size_t)MTOT*DM_*2);
  unsigned short* wqt = (unsigned short*)alloc((size_t)DM_*DM_*2);
  unsigned short* wkt = (unsigned short*)alloc((size_t)DM_*DM_*2);
  unsigned short* wvt = (unsigned short*)alloc((size_t)DM_*DM_*2);
  unsigned short* wot = (unsigned short*)alloc((size_t)DM_*DM_*2);
  float2*         tab = (float2*)alloc((size_t)NS_*30*sizeof(float2));
  unsigned short* Qb  = (unsigned short*)alloc((size_t)MTOT*DM_*2);
  unsigned short* Kb  = (unsigned short*)alloc((size_t)MTOT*DM_*2);
  unsigned short* Vb  = (unsigned short*)alloc((size_t)MTOT*DM_*2);
  unsigned short* VTb = (unsigned short*)alloc((size_t)MTOT*DM_*2);
  unsigned short* cxb = (unsigned short*)alloc((size_t)MTOT*DM_*2);

  k_cast_x<<<dim3(MTOT*DM_/1024), dim3(256), 0, stream>>>(hs, xb);
  k_wt<<<dim3(16,16), dim3(256), 0, stream>>>(Wq, wqt);
  k_wt<<<dim3(16,16), dim3(256), 0, stream>>>(Wk, wkt);
  k_wt<<<dim3(16,16), dim3(256), 0, stream>>>(Wv, wvt);
  k_wt<<<dim3(16,16), dim3(256), 0, stream>>>(Wo, wot);
  k_tab<<<dim3(32), dim3(64), 0, stream>>>(tab);

  k_gemm<0><<<dim3(8,64), dim3(256), 0, stream>>>(xb, wqt, bq, (void*)Qb);
  k_gemm<0><<<dim3(8,64), dim3(256), 0, stream>>>(xb, wkt, bk, (void*)Kb);
  k_gemm<0><<<dim3(8,64), dim3(256), 0, stream>>>(xb, wvt, bv, (void*)Vb);

  k_rope<<<dim3(64*NS_/16), dim3(256), 0, stream>>>(Qb, Kb, tab);
  k_vt<<<dim3(512), dim3(256), 0, stream>>>(Vb, VTb);

  k_attn<<<dim3(NS_/256, 64), dim3(512), 0, stream>>>(Qb, Kb, VTb, cxb);

  k_gemm<1><<<dim3(8,64), dim3(256), 0, stream>>>(cxb, wot, bo, d_out);
}

// Round 5
// 272.594 us; speedup vs baseline: 2.2417x; 1.0250x over previous
//
#include <hip/hip_runtime.h>
#include <stdint.h>

#define H_   16
#define NS_  2048
#define B_   4
#define DM_  1024
#define HD_  64
#define MTOT (B_*NS_)   // 8192 tokens

typedef __attribute__((ext_vector_type(8)))  short bf16x8;
typedef __attribute__((ext_vector_type(4)))  float f32x4;
typedef __attribute__((ext_vector_type(16))) float f32x16;

__device__ __forceinline__ unsigned short f2bf(float f){
  union { float f; unsigned u; } v; v.f = f;
  unsigned r = v.u + 0x7FFFu + ((v.u >> 16) & 1u);
  return (unsigned short)(r >> 16);
}
__device__ __forceinline__ float bf2f(unsigned short u){
  union { unsigned u; float f; } v; v.u = ((unsigned)u) << 16;
  return v.f;
}
__device__ __forceinline__ unsigned pk2(float a, float b){
  return (unsigned)f2bf(a) | ((unsigned)f2bf(b) << 16);
}
__device__ __forceinline__ void gll16(const void* g, void* l){
  __builtin_amdgcn_global_load_lds(
      (const __attribute__((address_space(1))) unsigned int*)g,
      (__attribute__((address_space(3))) unsigned int*)l,
      16, 0, 0);
}

// ---------------- cast hidden_states fp32 -> bf16 ----------------
__global__ void k_cast_x(const float* __restrict__ x, unsigned short* __restrict__ xb){
  long i = ((long)blockIdx.x*256 + threadIdx.x)*4;
  float4 v = *(const float4*)(x + i);
  ushort4 o; o.x=f2bf(v.x); o.y=f2bf(v.y); o.z=f2bf(v.z); o.w=f2bf(v.w);
  *(ushort4*)(xb + i) = o;
}

// ---------------- transpose-cast weight: W[k][n] fp32 -> Wt[n][k] bf16 ----------------
__global__ void k_wt(const float* __restrict__ W, unsigned short* __restrict__ Wt){
  __shared__ float tile[64][65];
  int kt = blockIdx.y*64, nt = blockIdx.x*64;
  int t = threadIdx.x;
  int r = t >> 4, c4 = (t & 15)*4;
#pragma unroll
  for (int i=0;i<4;i++){
    int k = r + i*16;
    float4 v = *(const float4*)(W + (size_t)(kt + k)*DM_ + nt + c4);
    tile[k][c4] = v.x; tile[k][c4+1]=v.y; tile[k][c4+2]=v.z; tile[k][c4+3]=v.w;
  }
  __syncthreads();
#pragma unroll
  for (int i=0;i<4;i++){
    int n = r + i*16;
    ushort4 o;
    o.x = f2bf(tile[c4+0][n]); o.y = f2bf(tile[c4+1][n]);
    o.z = f2bf(tile[c4+2][n]); o.w = f2bf(tile[c4+3][n]);
    *(ushort4*)(Wt + (size_t)(nt + n)*DM_ + kt + c4) = o;
  }
}

// ---------------- RoPE sin/cos table ----------------
__global__ void k_tab(float2* __restrict__ tab){
  int n = blockIdx.x*64 + threadIdx.x;
  int f = n >> 8, rem = n & 255, hh = rem >> 4, ww = rem & 15;
  float pos[3]; pos[0]=(float)f; pos[1]=(float)hh; pos[2]=(float)ww;
#pragma unroll
  for (int c=0;c<3;c++)
#pragma unroll
    for (int i=0;i<10;i++){
      float inv = exp2f(-(float)i * 1.3287712379549449f);  // 10000^(-i/10)
      float s, co;
      sincosf(pos[c]*inv, &s, &co);
      tab[n*30 + c*10 + i] = make_float2(co, s);
    }
}

// ---------------- fused QKV GEMM: A(8192x1024) @ {Wq,Wk,Wv}^T ----------------
// mat = blockIdx.x>>3.  Q,K -> (B,H,N,64) bf16.  V -> VT_perm (B,H,64,N) bf16
// with key index sigma-permuted (swap bits 2<->3) along N.
__global__ __launch_bounds__(256) void k_gemm_qkv(const unsigned short* __restrict__ A,
                                                  const unsigned short* __restrict__ wq,
                                                  const unsigned short* __restrict__ wk,
                                                  const unsigned short* __restrict__ wv,
                                                  const float* __restrict__ bq,
                                                  const float* __restrict__ bk,
                                                  const float* __restrict__ bv,
                                                  unsigned short* __restrict__ Qb,
                                                  unsigned short* __restrict__ Kb,
                                                  unsigned short* __restrict__ VTb)
{
  __shared__ unsigned short As[128*32];
  __shared__ unsigned short Bs[128*32];
  const int tid = threadIdx.x, lane = tid & 63, w = tid >> 6;
  const int mat = blockIdx.x >> 3;
  const int nt  = (blockIdx.x & 7)*128;
  const int mt  = blockIdx.y*128;
  const unsigned short* Wt  = (mat==0)? wq : (mat==1)? wk : wv;
  const float*          bias= (mat==0)? bq : (mat==1)? bk : bv;
  const int wm = (w >> 1)*64, wn = (w & 1)*64;
  const int qc = lane & 15, g = lane >> 4;
  f32x4 acc[4][4] = {};

  const unsigned short* gA = A  + (size_t)(mt + w*32 + (lane>>2))*DM_ + (lane&3)*8;
  const unsigned short* gB = Wt + (size_t)(nt + w*32 + (lane>>2))*DM_ + (lane&3)*8;
  unsigned short* lA = &As[(w*32)*32];
  unsigned short* lB = &Bs[(w*32)*32];

  for (int k0 = 0; k0 < DM_; k0 += 32){
    gll16(gA + k0,           lA);
    gll16(gA + k0 + 16*DM_,  lA + 16*32);
    gll16(gB + k0,           lB);
    gll16(gB + k0 + 16*DM_,  lB + 16*32);
    __syncthreads();
    bf16x8 af[4], bfr[4];
#pragma unroll
    for (int m=0;m<4;m++) af[m]  = *(const bf16x8*)&As[(wm + m*16 + qc)*32 + g*8];
#pragma unroll
    for (int n=0;n<4;n++) bfr[n] = *(const bf16x8*)&Bs[(wn + n*16 + qc)*32 + g*8];
#pragma unroll
    for (int m=0;m<4;m++)
#pragma unroll
      for (int n=0;n<4;n++)
        acc[m][n] = __builtin_amdgcn_mfma_f32_16x16x32_bf16(af[m], bfr[n], acc[m][n], 0,0,0);
    __syncthreads();
  }

  if (mat < 2){
    unsigned short* out = (mat==0)? Qb : Kb;
#pragma unroll
    for (int n=0;n<4;n++){
      int col = nt + wn + n*16 + qc;
      float bv_ = bias[col];
      int hh = col >> 6, d = col & 63;
#pragma unroll
      for (int m=0;m<4;m++){
#pragma unroll
        for (int r=0;r<4;r++){
          int mrow = mt + wm + m*16 + g*4 + r;
          size_t idx = (((size_t)(mrow >> 11)*H_ + hh)*NS_ + (mrow & (NS_-1)))*HD_ + d;
          out[idx] = f2bf(acc[m][n][r] + bv_);
        }
      }
    }
  } else {
#pragma unroll
    for (int n=0;n<4;n++){
      int col = nt + wn + n*16 + qc;
      float bv_ = bias[col];
      int hh = col >> 6, d = col & 63;
#pragma unroll
      for (int m=0;m<4;m++){
        int mrow0 = mt + wm + m*16 + g*4;     // r=0..3 consecutive tokens
        int b = mrow0 >> 11, ntk = mrow0 & (NS_-1);
        int pos = (ntk & ~12) | ((ntk & 4) << 1) | ((ntk & 8) >> 1);  // swap bits 2,3
        ushort4 o;
        o.x = f2bf(acc[m][n][0] + bv_);
        o.y = f2bf(acc[m][n][1] + bv_);
        o.z = f2bf(acc[m][n][2] + bv_);
        o.w = f2bf(acc[m][n][3] + bv_);
        *(ushort4*)(VTb + (((size_t)(b*H_ + hh)*HD_ + d)*NS_ + pos)) = o;
      }
    }
  }
}

// ---------------- in-place RoPE on Q,K; Q scaled by 0.125*log2(e) ----------------
#define QSCALE 0.18033688011112042f   // 0.125 * log2(e): softmax runs in log2 units
__global__ void k_rope(unsigned short* __restrict__ Qb, unsigned short* __restrict__ Kb,
                       const float2* __restrict__ tab)
{
  const int t = threadIdx.x;
  const int d4 = (t & 15)*4;
  const long gtok = (long)blockIdx.x*16 + (t >> 4);
  size_t base = (size_t)gtok*HD_ + d4;
  if (d4 >= 60){
    ushort4 v = *(ushort4*)(Qb + base);
    ushort4 o;
    o.x = f2bf(bf2f(v.x)*QSCALE); o.y = f2bf(bf2f(v.y)*QSCALE);
    o.z = f2bf(bf2f(v.z)*QSCALE); o.w = f2bf(bf2f(v.w)*QSCALE);
    *(ushort4*)(Qb + base) = o;
    return;
  }
  const int n = (int)(gtok & (NS_-1));
  const int c = d4 / 20;
  const int dd = d4 - c*20;
  const float2* tb = tab + n*30 + c*10;
  float2 cs0 = tb[(dd+0) % 10];
  float2 cs1 = tb[(dd+1) % 10];
  float2 cs2 = tb[(dd+2) % 10];
  float2 cs3 = tb[(dd+3) % 10];
#pragma unroll
  for (int which = 0; which < 2; which++){
    unsigned short* P = which ? Kb : Qb;
    float sc = which ? 1.f : QSCALE;
    ushort4 v = *(ushort4*)(P + base);
    float x0=bf2f(v.x), x1=bf2f(v.y), x2=bf2f(v.z), x3=bf2f(v.w);
    ushort4 o;
    o.x = f2bf((x0*cs0.x - x1*cs0.y)*sc);
    o.y = f2bf((x1*cs1.x + x0*cs1.y)*sc);
    o.z = f2bf((x2*cs2.x - x3*cs2.y)*sc);
    o.w = f2bf((x3*cs3.x + x2*cs3.y)*sc);
    *(ushort4*)(P + base) = o;
  }
}

// ---------------- 8-warp flash attention, 32x32 MFMA, swapped QK^T ----------------
// grid (bh=64, qblk=8): all 8 q-blocks of a head share an XCD (id = bh mod 8).
// Softmax in log2 units, defer-max THR=11.5, per-lane partial l (combined once
// at end). P fragment lane-local (RTNE f2bf); V read is a single b128 thanks
// to the sigma-permuted VT layout (keys bit2<->bit3 swapped).
__global__ __launch_bounds__(512, 4) void k_attn(const unsigned short* __restrict__ Q,
                                                 const unsigned short* __restrict__ K,
                                                 const unsigned short* __restrict__ VT,
                                                 unsigned short* __restrict__ ctxout)
{
  __shared__ __attribute__((aligned(16))) char smem[32768]; // 2 bufs x (8KB K + 8KB VT)
  const int tid  = threadIdx.x;
  const int lane = tid & 63, w = tid >> 6;
  const int qcol = lane & 31, h = lane >> 5;
  const int sw   = (lane & 7) << 4;
  const int bh   = blockIdx.x;
  const int q0   = blockIdx.y*256 + w*32;

  const unsigned short* Qp = Q  + ((size_t)bh*NS_ + q0)*HD_;
  const unsigned short* Kp = K  + (size_t)bh*NS_*HD_;
  const unsigned short* Vp = VT + (size_t)bh*HD_*NS_;

  // staging map: thread t covers LDS chunk (row=t>>3, c=t&7); global chunk = c ^ (row&7)
  const int trow = tid >> 3;
  const int tc   = (tid & 7) ^ (trow & 7);

  bf16x8 qf[4];
#pragma unroll
  for (int i=0;i<4;i++)
    qf[i] = *(const bf16x8*)(Qp + (size_t)qcol*HD_ + 16*i + 8*h);

  // stage tile 0 into buffer 0
  {
    const unsigned short* gk = Kp + (size_t)trow*HD_ + tc*8;
    const unsigned short* gv = Vp + (size_t)trow*NS_ + tc*8;
    gll16(gk, smem + w*1024);
    gll16(gv, smem + 8192 + w*1024);
  }

  f32x16 ctx0 = {}, ctx1 = {};
  float mrun = -1e30f, lp = 0.f;

  for (int t = 0; t < NS_/64; ++t){
    const int curo = (t & 1) * 16384;
    __syncthreads();                      // barrier drains vmcnt: stage(cur) complete
    if (t + 1 < NS_/64){
      const int kb = (t+1)*64;
      const int nxt = ((t+1) & 1) * 16384;
      const unsigned short* gk = Kp + (size_t)(kb + trow)*HD_ + tc*8;
      const unsigned short* gv = Vp + (size_t)trow*NS_ + kb + tc*8;
      gll16(gk, smem + nxt + w*1024);
      gll16(gv, smem + nxt + 8192 + w*1024);
    }
    const char* kls = smem + curo;
    const char* vls = smem + curo + 8192;

#pragma unroll
    for (int s = 0; s < 2; ++s){          // two 32-key subtiles
      f32x16 st = {};
#pragma unroll
      for (int i=0;i<4;i++){
        bf16x8 kf = *(const bf16x8*)(kls + ((((32*s + qcol)*128) + 32*i + 16*h) ^ sw));
        st = __builtin_amdgcn_mfma_f32_32x32x16_bf16(kf, qf[i], st, 0,0,0);
      }
      // ---- local max (max3-friendly tree), defer-max in log2 units ----
      float a0 = fmaxf(fmaxf(st[0],  st[1]),  st[2]);
      float a1 = fmaxf(fmaxf(st[3],  st[4]),  st[5]);
      float a2 = fmaxf(fmaxf(st[6],  st[7]),  st[8]);
      float a3 = fmaxf(fmaxf(st[9],  st[10]), st[11]);
      float a4 = fmaxf(fmaxf(st[12], st[13]), st[14]);
      float tm = fmaxf(fmaxf(fmaxf(a0,a1),a2), fmaxf(fmaxf(a3,a4),st[15]));
      if (!__all(tm - mrun <= 11.5f)){
        float tp = fmaxf(tm, __shfl_xor(tm, 32));
        float mnew = fmaxf(mrun, tp);
        float alpha = exp2f(mrun - mnew);
        lp *= alpha;
#pragma unroll
        for (int r=0;r<16;r++){ ctx0[r]*=alpha; ctx1[r]*=alpha; }
        mrun = mnew;
      }
      float p_[16]; float ps = 0.f;
#pragma unroll
      for (int r=0;r<16;r++){ p_[r] = exp2f(st[r] - mrun); ps += p_[r]; }
      lp += ps;

      // ---- P fragments: lane-local, RTNE f2bf (proven numerics) ----
      bf16x8 pf0, pf1;
#pragma unroll
      for (int e=0;e<8;e++){
        pf0[e] = (short)f2bf(p_[e]);
        pf1[e] = (short)f2bf(p_[8+e]);
      }

      // ---- PV: single b128 V fragment (sigma-permuted storage) ----
#pragma unroll
      for (int kc=0; kc<2; ++kc){
        const bf16x8 pf = kc ? pf1 : pf0;
        bf16x8 vf0 = *(const bf16x8*)(vls + ((qcol)*128      + ((64*s + 32*kc + 16*h) ^ sw)));
        ctx0 = __builtin_amdgcn_mfma_f32_32x32x16_bf16(vf0, pf, ctx0, 0,0,0);
        bf16x8 vf1 = *(const bf16x8*)(vls + ((32 + qcol)*128 + ((64*s + 32*kc + 16*h) ^ sw)));
        ctx1 = __builtin_amdgcn_mfma_f32_32x32x16_bf16(vf1, pf, ctx1, 0,0,0);
      }
    }
  }

  float lsum = lp + __shfl_xor(lp, 32);
  float linv = 1.f / lsum;
  __syncthreads();                         // all warps done reading K/V LDS
  char* reg = smem + w*4096;               // 4KB per warp: [32 q][64 d] bf16
#pragma unroll
  for (int rq=0; rq<4; ++rq){
    int db0 = 8*rq + 4*h;
    uint2 v0, v1;
    v0.x = pk2(ctx0[4*rq+0]*linv, ctx0[4*rq+1]*linv);
    v0.y = pk2(ctx0[4*rq+2]*linv, ctx0[4*rq+3]*linv);
    v1.x = pk2(ctx1[4*rq+0]*linv, ctx1[4*rq+1]*linv);
    v1.y = pk2(ctx1[4*rq+2]*linv, ctx1[4*rq+3]*linv);
    *(uint2*)(reg + qcol*128 + db0*2)      = v0;
    *(uint2*)(reg + qcol*128 + (32+db0)*2) = v1;
  }
  __syncthreads();
  const int b = bh >> 4, head = bh & 15;
  unsigned short* outp = ctxout + ((size_t)b*NS_ + q0)*DM_ + head*HD_;
#pragma unroll
  for (int p=0;p<4;p++){
    int row = p*8 + (lane>>3);
    uint4 v = *(const uint4*)(reg + row*128 + (lane&7)*16);
    *(uint4*)(outp + (size_t)row*DM_ + (lane&7)*8) = v;
  }
}

// ---------------- output projection GEMM (fp32 out) ----------------
__global__ __launch_bounds__(256) void k_gemm_o(const unsigned short* __restrict__ A,
                                                const unsigned short* __restrict__ Wt,
                                                const float* __restrict__ bias,
                                                float* __restrict__ out)
{
  __shared__ unsigned short As[128*32];
  __shared__ unsigned short Bs[128*32];
  const int tid = threadIdx.x, lane = tid & 63, w = tid >> 6;
  const int mt = blockIdx.y*128, nt = blockIdx.x*128;
  const int wm = (w >> 1)*64, wn = (w & 1)*64;
  const int qc = lane & 15, g = lane >> 4;
  f32x4 acc[4][4] = {};

  const unsigned short* gA = A  + (size_t)(mt + w*32 + (lane>>2))*DM_ + (lane&3)*8;
  const unsigned short* gB = Wt + (size_t)(nt + w*32 + (lane>>2))*DM_ + (lane&3)*8;
  unsigned short* lA = &As[(w*32)*32];
  unsigned short* lB = &Bs[(w*32)*32];

  for (int k0 = 0; k0 < DM_; k0 += 32){
    gll16(gA + k0,           lA);
    gll16(gA + k0 + 16*DM_,  lA + 16*32);
    gll16(gB + k0,           lB);
    gll16(gB + k0 + 16*DM_,  lB + 16*32);
    __syncthreads();
    bf16x8 af[4], bfr[4];
#pragma unroll
    for (int m=0;m<4;m++) af[m]  = *(const bf16x8*)&As[(wm + m*16 + qc)*32 + g*8];
#pragma unroll
    for (int n=0;n<4;n++) bfr[n] = *(const bf16x8*)&Bs[(wn + n*16 + qc)*32 + g*8];
#pragma unroll
    for (int m=0;m<4;m++)
#pragma unroll
      for (int n=0;n<4;n++)
        acc[m][n] = __builtin_amdgcn_mfma_f32_16x16x32_bf16(af[m], bfr[n], acc[m][n], 0,0,0);
    __syncthreads();
  }

#pragma unroll
  for (int n=0;n<4;n++){
    int col = nt + wn + n*16 + qc;
    float bv = bias[col];
#pragma unroll
    for (int m=0;m<4;m++){
#pragma unroll
      for (int r=0;r<4;r++){
        int mrow = mt + wm + m*16 + g*4 + r;
        out[(size_t)mrow*DM_ + col] = acc[m][n][r] + bv;
      }
    }
  }
}

extern "C" void kernel_launch(void* const* d_in, const int* in_sizes, int n_in,
                              void* d_out, int out_size, void* d_ws, size_t ws_size,
                              hipStream_t stream)
{
  const float* hs = (const float*)d_in[0];
  const float* Wq = (const float*)d_in[1];
  const float* bq = (const float*)d_in[2];
  const float* Wk = (const float*)d_in[3];
  const float* bk = (const float*)d_in[4];
  const float* Wv = (const float*)d_in[5];
  const float* bv = (const float*)d_in[6];
  const float* Wo = (const float*)d_in[7];
  const float* bo = (const float*)d_in[8];

  char* ws = (char*)d_ws;
  size_t off = 0;
  auto alloc = [&](size_t b){ void* p = ws + off; off += (b + 255) & ~(size_t)255; return p; };
  unsigned short* xb  = (unsigned short*)alloc((size_t)MTOT*DM_*2);
  unsigned short* wqt = (unsigned short*)alloc((size_t)DM_*DM_*2);
  unsigned short* wkt = (unsigned short*)alloc((size_t)DM_*DM_*2);
  unsigned short* wvt = (unsigned short*)alloc((size_t)DM_*DM_*2);
  unsigned short* wot = (unsigned short*)alloc((size_t)DM_*DM_*2);
  float2*         tab = (float2*)alloc((size_t)NS_*30*sizeof(float2));
  unsigned short* Qb  = (unsigned short*)alloc((size_t)MTOT*DM_*2);
  unsigned short* Kb  = (unsigned short*)alloc((size_t)MTOT*DM_*2);
  unsigned short* VTb = (unsigned short*)alloc((size_t)MTOT*DM_*2);
  unsigned short* cxb = (unsigned short*)alloc((size_t)MTOT*DM_*2);

  k_cast_x<<<dim3(MTOT*DM_/1024), dim3(256), 0, stream>>>(hs, xb);
  k_wt<<<dim3(16,16), dim3(256), 0, stream>>>(Wq, wqt);
  k_wt<<<dim3(16,16), dim3(256), 0, stream>>>(Wk, wkt);
  k_wt<<<dim3(16,16), dim3(256), 0, stream>>>(Wv, wvt);
  k_wt<<<dim3(16,16), dim3(256), 0, stream>>>(Wo, wot);
  k_tab<<<dim3(32), dim3(64), 0, stream>>>(tab);

  k_gemm_qkv<<<dim3(24,64), dim3(256), 0, stream>>>(xb, wqt, wkt, wvt, bq, bk, bv,
                                                    Qb, Kb, VTb);

  k_rope<<<dim3(64*NS_/16), dim3(256), 0, stream>>>(Qb, Kb, tab);

  k_attn<<<dim3(64, NS_/256), dim3(512), 0, stream>>>(Qb, Kb, VTb, cxb);

  k_gemm_o<<<dim3(8,64), dim3(256), 0, stream>>>(cxb, wot, bo, (float*)d_out);
}